// Round 1
// baseline (151.383 us; speedup 1.0000x reference)
//
#include <hip/hip_runtime.h>
#include <hip/hip_bf16.h>
#include <float.h>

#define N_PATCH 216
#define DIM 125
#define HEADS 8
#define HEAD_DIM 64
#define QK 512           // HEADS*HEAD_DIM
#define NH (HEADS*N_PATCH)   // 1728

// ws layout (floats):
//  q   : [216][512]   off 0        (110592)
//  k   : [216][512]   off 110592   (110592)
//  stats: [16][2]     off 221184   (32)   bid<8: q-head h; bid>=8: k-head h  {mean,var}
//  Qt  : [8][64][216] off 221216   (110592)  (transposed for coalesced score reads)
//  Kn  : [8][216][64] off 331808   (110592)
//  x4  : [72][72][72] off 442400   (373248)
//  t1  : [20][72][72] off 815648   (103680)
//  t2  : [20][20][72] off 919328   (28800)
//  total 948128 floats = 3.62 MB

__global__ __launch_bounds__(256) void k_qk(const float* __restrict__ x,
        const float* __restrict__ Wq, const float* __restrict__ Wk,
        float* __restrict__ q, float* __restrict__ k) {
    __shared__ float xs[DIM];
    const int n = blockIdx.x, t = threadIdx.x;
    if (t < DIM) xs[t] = x[n*DIM + t];
    __syncthreads();
    #pragma unroll
    for (int rep = 0; rep < 4; ++rep) {
        int c = t + rep*256;                 // 0..1023: 0-511 q rows, 512-1023 k rows
        const float* W = (c < QK) ? (Wq + c*DIM) : (Wk + (c-QK)*DIM);
        float acc = 0.f;
        #pragma unroll 5
        for (int i = 0; i < DIM; ++i) acc += xs[i]*W[i];
        if (c < QK) q[n*QK + c] = acc; else k[n*QK + (c-QK)] = acc;
    }
}

__global__ __launch_bounds__(256) void k_stats(const float* __restrict__ q,
        const float* __restrict__ k, float* __restrict__ stats) {
    const int bid = blockIdx.x;              // 0..15
    const int t = threadIdx.x;
    const float* src = (bid < 8) ? q : k;
    const int h = bid & 7;
    float s = 0.f, ss = 0.f;
    for (int idx = t; idx < N_PATCH*HEAD_DIM; idx += 256) {
        int n = idx >> 6, d = idx & 63;
        float v = src[n*QK + h*HEAD_DIM + d];
        s += v; ss += v*v;
    }
    for (int off = 32; off; off >>= 1) {
        s  += __shfl_down(s,  off, 64);
        ss += __shfl_down(ss, off, 64);
    }
    __shared__ float rs[4], rss[4];
    int wv = t >> 6, lane = t & 63;
    if (lane == 0) { rs[wv] = s; rss[wv] = ss; }
    __syncthreads();
    if (t == 0) {
        float S = rs[0]+rs[1]+rs[2]+rs[3];
        float SS = rss[0]+rss[1]+rss[2]+rss[3];
        const float invN = 1.0f/13824.0f;
        float mean = S*invN;
        float var  = SS*invN - mean*mean;
        stats[bid*2]   = mean;
        stats[bid*2+1] = var;
    }
}

__global__ __launch_bounds__(256) void k_norm(const float* __restrict__ q,
        const float* __restrict__ k, const float* __restrict__ stats,
        const float* __restrict__ bnw, const float* __restrict__ bnb,
        float* __restrict__ Qt, float* __restrict__ Kn) {
    int gw = blockIdx.x*4 + (threadIdx.x >> 6);   // 0..3455
    int lane = threadIdx.x & 63;
    int isK = (gw >= NH) ? 1 : 0;
    int r = isK ? gw - NH : gw;
    int h = r / N_PATCH, n = r % N_PATCH;
    const float* src = isK ? k : q;
    int sb = (isK*8 + h)*2;
    float mean = stats[sb], var = stats[sb+1];
    float inv = 1.0f / sqrtf(var + 1e-5f);
    float w = bnw[h], b = bnb[h];
    float v = src[n*QK + h*HEAD_DIM + lane];
    float xh = (v - mean)*inv*w + b;
    float sq = xh*xh;
    for (int off = 32; off; off >>= 1) sq += __shfl_xor(sq, off, 64);
    float nrm = fmaxf(sqrtf(sq), 1e-12f);
    float o = xh / nrm;
    if (isK) Kn[(h*N_PATCH + n)*HEAD_DIM + lane] = o;
    else     Qt[h*HEAD_DIM*N_PATCH + lane*N_PATCH + n] = o;
}

// One block per output column c = h*216 + m. Sparsemax over n (216 values).
__global__ __launch_bounds__(256) void k_sparsemax(const float* __restrict__ Qt,
        const float* __restrict__ Kn, float* __restrict__ att, float* __restrict__ x4) {
    const int c = blockIdx.x;
    const int h = c / N_PATCH, m = c % N_PATCH;
    const int tid = threadIdx.x;
    __shared__ float ks[HEAD_DIM];
    __shared__ float sz[256];
    __shared__ float wtot[4], rk[4], rssum[4];
    if (tid < HEAD_DIM) ks[tid] = Kn[(h*N_PATCH+m)*HEAD_DIM + tid];
    __syncthreads();
    float z = 0.f;
    const float* qt = Qt + h*HEAD_DIM*N_PATCH;
    if (tid < N_PATCH) {
        #pragma unroll 8
        for (int d = 0; d < HEAD_DIM; ++d) z += qt[d*N_PATCH + tid]*ks[d];
        z *= 0.08944271909999159f;           // 1/sqrt(125)
    }
    sz[tid] = (tid < N_PATCH) ? z : -FLT_MAX;
    __syncthreads();
    // bitonic sort, descending, 256 elems
    for (int kk = 2; kk <= 256; kk <<= 1) {
        for (int j = kk >> 1; j > 0; j >>= 1) {
            int ixj = tid ^ j;
            if (ixj > tid) {
                float a = sz[tid], bb = sz[ixj];
                bool desc = ((tid & kk) == 0);
                if (desc ? (a < bb) : (a > bb)) { sz[tid] = bb; sz[ixj] = a; }
            }
            __syncthreads();
        }
    }
    // inclusive scan of sorted values
    float sv = sz[tid];
    int lane = tid & 63, wv = tid >> 6;
    float cs = sv;
    for (int off = 1; off < 64; off <<= 1) {
        float t = __shfl_up(cs, off, 64);
        if (lane >= off) cs += t;
    }
    if (lane == 63) wtot[wv] = cs;
    __syncthreads();
    for (int p = 0; p < wv; ++p) cs += wtot[p];
    // support set
    float supp = 0.f, ssel = 0.f;
    if (tid < N_PATCH && (1.0f + (float)(tid+1)*sv > cs)) { supp = 1.f; ssel = sv; }
    float s1 = supp, s2 = ssel;
    for (int off = 32; off; off >>= 1) {
        s1 += __shfl_xor(s1, off, 64);
        s2 += __shfl_xor(s2, off, 64);
    }
    if (lane == 0) { rk[wv] = s1; rssum[wv] = s2; }
    __syncthreads();
    float kstar = rk[0]+rk[1]+rk[2]+rk[3];
    float ssum  = rssum[0]+rssum[1]+rssum[2]+rssum[3];
    float tau = (ssum - 1.0f)/kstar;
    if (tid < N_PATCH) {
        float a = fmaxf(z - tau, 0.0f);
        att[tid*NH + c] = a;
        // permute (2,2,2,6,6,6,6,6,6) -> axes (0,3,6,1,4,7,2,5,8) -> [72,72,72]
        int nh2 = tid / 27;
        int d0 = nh2 >> 2, d1 = (nh2 >> 1) & 1, d2 = nh2 & 1;
        int r = (tid % 27)*NH + c;
        int d3 = r / 7776; r -= d3*7776;
        int d4 = r / 1296; r -= d4*1296;
        int d5 = r / 216;  r -= d5*216;
        int d6 = r / 36;   r -= d6*36;
        int d7 = r / 6;
        int d8 = r - d7*6;
        int ii  = d0*36 + d3*6 + d6;
        int jj  = d1*36 + d4*6 + d7;
        int kk2 = d2*36 + d5*6 + d8;
        x4[(ii*72 + jj)*72 + kk2] = a;
    }
}

__global__ __launch_bounds__(256) void k_tcl1(const float* __restrict__ W1,
        const float* __restrict__ x4, float* __restrict__ t1) {
    int o = blockIdx.x*256 + threadIdx.x;    // exactly 103680
    int a = o / 5184, jk = o % 5184;
    float acc = 0.f;
    #pragma unroll 8
    for (int i = 0; i < 72; ++i) acc += W1[a*72+i]*x4[i*5184 + jk];
    t1[o] = acc;
}

__global__ __launch_bounds__(256) void k_tcl2(const float* __restrict__ W2,
        const float* __restrict__ t1, float* __restrict__ t2) {
    int o = blockIdx.x*256 + threadIdx.x;
    if (o >= 28800) return;
    int a = o / 1440, rem = o % 1440;
    int cc = rem / 72, kk = rem % 72;
    float acc = 0.f;
    #pragma unroll 8
    for (int j = 0; j < 72; ++j) acc += W2[cc*72+j]*t1[a*5184 + j*72 + kk];
    t2[o] = acc;
}

__global__ __launch_bounds__(256) void k_tcl3(const float* __restrict__ W3,
        const float* __restrict__ t2, float* __restrict__ out0) {
    int o = blockIdx.x*256 + threadIdx.x;
    if (o >= 8000) return;
    int a = o / 400, rem = o % 400;
    int cc = rem / 20, dd = rem % 20;
    float acc = 0.f;
    #pragma unroll 8
    for (int k = 0; k < 72; ++k) acc += W3[dd*72+k]*t2[(a*20+cc)*72 + k];
    out0[o] = tanhf(acc);
}

extern "C" void kernel_launch(void* const* d_in, const int* in_sizes, int n_in,
                              void* d_out, int out_size, void* d_ws, size_t ws_size,
                              hipStream_t stream) {
    const float* patches = (const float*)d_in[0];
    const float* Wq = (const float*)d_in[1];
    const float* Wk = (const float*)d_in[2];
    const float* bnw = (const float*)d_in[3];
    const float* bnb = (const float*)d_in[4];
    const float* W1 = (const float*)d_in[5];
    const float* W2 = (const float*)d_in[6];
    const float* W3 = (const float*)d_in[7];
    float* out = (float*)d_out;
    float* ws = (float*)d_ws;

    float* q     = ws;
    float* k     = ws + 110592;
    float* stats = ws + 221184;
    float* Qt    = ws + 221216;
    float* Kn    = ws + 331808;
    float* x4    = ws + 442400;
    float* t1    = ws + 815648;
    float* t2    = ws + 919328;

    float* out0 = out;          // tanh(x5): 8000 floats
    float* att  = out + 8000;   // att: 216*1728 floats

    hipLaunchKernelGGL(k_qk,        dim3(216),  dim3(256), 0, stream, patches, Wq, Wk, q, k);
    hipLaunchKernelGGL(k_stats,     dim3(16),   dim3(256), 0, stream, q, k, stats);
    hipLaunchKernelGGL(k_norm,      dim3(864),  dim3(256), 0, stream, q, k, stats, bnw, bnb, Qt, Kn);
    hipLaunchKernelGGL(k_sparsemax, dim3(1728), dim3(256), 0, stream, Qt, Kn, att, x4);
    hipLaunchKernelGGL(k_tcl1,      dim3(405),  dim3(256), 0, stream, W1, x4, t1);
    hipLaunchKernelGGL(k_tcl2,      dim3(113),  dim3(256), 0, stream, W2, t1, t2);
    hipLaunchKernelGGL(k_tcl3,      dim3(32),   dim3(256), 0, stream, W3, t2, out0);
}

// Round 2
// 135.316 us; speedup vs baseline: 1.1187x; 1.1187x over previous
//
#include <hip/hip_runtime.h>
#include <hip/hip_bf16.h>
#include <float.h>

#define N_PATCH 216
#define DIM 125
#define HEADS 8
#define HEAD_DIM 64
#define QK 512           // HEADS*HEAD_DIM
#define NH (HEADS*N_PATCH)   // 1728

// ws layout (floats):
//  Wt  : [125][1024]  off 0        (128000)  cols 0-511 = Wq rows, 512-1023 = Wk rows
//  q   : [216][512]   off 128000   (110592)
//  k   : [216][512]   off 238592   (110592)
//  stats: [16][2]     off 349184   (32)
//  Qt  : [8][64][216] off 349216   (110592)
//  Kn  : [8][216][64] off 459808   (110592)
//  x4  : [72][72][72] off 570400   (373248)
//  t1  : [20][72][72] off 943648   (103680)
//  t2  : [20][20][72] off 1047328  (28800)

// Transpose Wq/Wk [1024 rows][125] -> Wt [125][1024], coalesced both sides via LDS.
__global__ __launch_bounds__(256) void k_wt(const float* __restrict__ Wq,
        const float* __restrict__ Wk, float* __restrict__ Wt) {
    __shared__ float lds[64*DIM];            // 32 KB
    const int bid = blockIdx.x;              // 0..15, 64 W-rows each
    const int t = threadIdx.x;
    const float* src = (bid < 8) ? Wq : Wk;
    const int rbase = (bid & 7)*64*DIM;
    for (int idx = t; idx < 64*DIM; idx += 256)
        lds[idx] = src[rbase + idx];         // fully contiguous
    __syncthreads();
    const int lane = t & 63, ii = t >> 6;
    const int c0 = bid*64;
    for (int i = ii; i < DIM; i += 4)
        Wt[i*1024 + c0 + lane] = lds[lane*DIM + i];   // stride-125 LDS read: conflict-free
}

__global__ __launch_bounds__(512) void k_qk(const float* __restrict__ x,
        const float* __restrict__ Wt, float* __restrict__ q, float* __restrict__ k) {
    __shared__ float xs[DIM];
    const int n = blockIdx.x, t = threadIdx.x;
    if (t < DIM) xs[t] = x[n*DIM + t];
    __syncthreads();
    const float2* Wt2 = (const float2*)Wt;
    float2 acc = {0.f, 0.f};
    #pragma unroll 5
    for (int i = 0; i < DIM; ++i) {
        float2 w = Wt2[i*512 + t];           // lanes consecutive -> coalesced
        float xv = xs[i];
        acc.x = fmaf(xv, w.x, acc.x);
        acc.y = fmaf(xv, w.y, acc.y);
    }
    int c = 2*t;
    if (c < QK) *(float2*)(q + n*QK + c) = acc;
    else        *(float2*)(k + n*QK + (c - QK)) = acc;
}

__global__ __launch_bounds__(256) void k_stats(const float* __restrict__ q,
        const float* __restrict__ k, float* __restrict__ stats) {
    const int bid = blockIdx.x;              // 0..15
    const int t = threadIdx.x;
    const float* src = (bid < 8) ? q : k;
    const int h = bid & 7;
    float s = 0.f, ss = 0.f;
    for (int idx = t; idx < N_PATCH*HEAD_DIM; idx += 256) {
        int n = idx >> 6, d = idx & 63;
        float v = src[n*QK + h*HEAD_DIM + d];
        s += v; ss += v*v;
    }
    for (int off = 32; off; off >>= 1) {
        s  += __shfl_down(s,  off, 64);
        ss += __shfl_down(ss, off, 64);
    }
    __shared__ float rs[4], rss[4];
    int wv = t >> 6, lane = t & 63;
    if (lane == 0) { rs[wv] = s; rss[wv] = ss; }
    __syncthreads();
    if (t == 0) {
        float S = rs[0]+rs[1]+rs[2]+rs[3];
        float SS = rss[0]+rss[1]+rss[2]+rss[3];
        const float invN = 1.0f/13824.0f;
        float mean = S*invN;
        float var  = SS*invN - mean*mean;
        stats[bid*2]   = mean;
        stats[bid*2+1] = var;
    }
}

__global__ __launch_bounds__(256) void k_norm(const float* __restrict__ q,
        const float* __restrict__ k, const float* __restrict__ stats,
        const float* __restrict__ bnw, const float* __restrict__ bnb,
        float* __restrict__ Qt, float* __restrict__ Kn) {
    int gw = blockIdx.x*4 + (threadIdx.x >> 6);   // 0..3455
    int lane = threadIdx.x & 63;
    int isK = (gw >= NH) ? 1 : 0;
    int r = isK ? gw - NH : gw;
    int h = r / N_PATCH, n = r % N_PATCH;
    const float* src = isK ? k : q;
    int sb = (isK*8 + h)*2;
    float mean = stats[sb], var = stats[sb+1];
    float inv = 1.0f / sqrtf(var + 1e-5f);
    float w = bnw[h], b = bnb[h];
    float v = src[n*QK + h*HEAD_DIM + lane];
    float xh = (v - mean)*inv*w + b;
    float sq = xh*xh;
    for (int off = 32; off; off >>= 1) sq += __shfl_xor(sq, off, 64);
    float nrm = fmaxf(sqrtf(sq), 1e-12f);
    float o = xh / nrm;
    if (isK) Kn[(h*N_PATCH + n)*HEAD_DIM + lane] = o;
    else     Qt[h*HEAD_DIM*N_PATCH + lane*N_PATCH + n] = o;
}

// One block per output column c = h*216 + m. Sparsemax over n (216 values).
__global__ __launch_bounds__(256) void k_sparsemax(const float* __restrict__ Qt,
        const float* __restrict__ Kn, float* __restrict__ att, float* __restrict__ x4) {
    const int c = blockIdx.x;
    const int h = c / N_PATCH, m = c % N_PATCH;
    const int tid = threadIdx.x;
    __shared__ float ks[HEAD_DIM];
    __shared__ float sz[256];
    __shared__ float wtot[4], rk[4], rssum[4];
    if (tid < HEAD_DIM) ks[tid] = Kn[(h*N_PATCH+m)*HEAD_DIM + tid];
    __syncthreads();
    float z = 0.f;
    const float* qt = Qt + h*HEAD_DIM*N_PATCH;
    if (tid < N_PATCH) {
        #pragma unroll 8
        for (int d = 0; d < HEAD_DIM; ++d) z += qt[d*N_PATCH + tid]*ks[d];
        z *= 0.08944271909999159f;           // 1/sqrt(125)
    }
    sz[tid] = (tid < N_PATCH) ? z : -FLT_MAX;
    __syncthreads();
    // bitonic sort, descending, 256 elems
    for (int kk = 2; kk <= 256; kk <<= 1) {
        for (int j = kk >> 1; j > 0; j >>= 1) {
            int ixj = tid ^ j;
            if (ixj > tid) {
                float a = sz[tid], bb = sz[ixj];
                bool desc = ((tid & kk) == 0);
                if (desc ? (a < bb) : (a > bb)) { sz[tid] = bb; sz[ixj] = a; }
            }
            __syncthreads();
        }
    }
    // inclusive scan of sorted values
    float sv = sz[tid];
    int lane = tid & 63, wv = tid >> 6;
    float cs = sv;
    for (int off = 1; off < 64; off <<= 1) {
        float t = __shfl_up(cs, off, 64);
        if (lane >= off) cs += t;
    }
    if (lane == 63) wtot[wv] = cs;
    __syncthreads();
    for (int p = 0; p < wv; ++p) cs += wtot[p];
    // support set
    float supp = 0.f, ssel = 0.f;
    if (tid < N_PATCH && (1.0f + (float)(tid+1)*sv > cs)) { supp = 1.f; ssel = sv; }
    float s1 = supp, s2 = ssel;
    for (int off = 32; off; off >>= 1) {
        s1 += __shfl_xor(s1, off, 64);
        s2 += __shfl_xor(s2, off, 64);
    }
    if (lane == 0) { rk[wv] = s1; rssum[wv] = s2; }
    __syncthreads();
    float kstar = rk[0]+rk[1]+rk[2]+rk[3];
    float ssum  = rssum[0]+rssum[1]+rssum[2]+rssum[3];
    float tau = (ssum - 1.0f)/kstar;
    if (tid < N_PATCH) {
        float a = fmaxf(z - tau, 0.0f);
        att[tid*NH + c] = a;
        // permute (2,2,2,6,6,6,6,6,6) -> axes (0,3,6,1,4,7,2,5,8) -> [72,72,72]
        int nh2 = tid / 27;
        int d0 = nh2 >> 2, d1 = (nh2 >> 1) & 1, d2 = nh2 & 1;
        int r = (tid % 27)*NH + c;
        int d3 = r / 7776; r -= d3*7776;
        int d4 = r / 1296; r -= d4*1296;
        int d5 = r / 216;  r -= d5*216;
        int d6 = r / 36;   r -= d6*36;
        int d7 = r / 6;
        int d8 = r - d7*6;
        int ii  = d0*36 + d3*6 + d6;
        int jj  = d1*36 + d4*6 + d7;
        int kk2 = d2*36 + d5*6 + d8;
        x4[(ii*72 + jj)*72 + kk2] = a;
    }
}

__global__ __launch_bounds__(256) void k_tcl1(const float* __restrict__ W1,
        const float* __restrict__ x4, float* __restrict__ t1) {
    int o = blockIdx.x*256 + threadIdx.x;    // exactly 103680
    int a = o / 5184, jk = o % 5184;
    float acc = 0.f;
    #pragma unroll 8
    for (int i = 0; i < 72; ++i) acc += W1[a*72+i]*x4[i*5184 + jk];
    t1[o] = acc;
}

__global__ __launch_bounds__(256) void k_tcl2(const float* __restrict__ W2,
        const float* __restrict__ t1, float* __restrict__ t2) {
    int o = blockIdx.x*256 + threadIdx.x;
    if (o >= 28800) return;
    int a = o / 1440, rem = o % 1440;
    int cc = rem / 72, kk = rem % 72;
    float acc = 0.f;
    #pragma unroll 8
    for (int j = 0; j < 72; ++j) acc += W2[cc*72+j]*t1[a*5184 + j*72 + kk];
    t2[o] = acc;
}

__global__ __launch_bounds__(256) void k_tcl3(const float* __restrict__ W3,
        const float* __restrict__ t2, float* __restrict__ out0) {
    int o = blockIdx.x*256 + threadIdx.x;
    if (o >= 8000) return;
    int a = o / 400, rem = o % 400;
    int cc = rem / 20, dd = rem % 20;
    float acc = 0.f;
    #pragma unroll 8
    for (int k = 0; k < 72; ++k) acc += W3[dd*72+k]*t2[(a*20+cc)*72 + k];
    out0[o] = tanhf(acc);
}

extern "C" void kernel_launch(void* const* d_in, const int* in_sizes, int n_in,
                              void* d_out, int out_size, void* d_ws, size_t ws_size,
                              hipStream_t stream) {
    const float* patches = (const float*)d_in[0];
    const float* Wq = (const float*)d_in[1];
    const float* Wk = (const float*)d_in[2];
    const float* bnw = (const float*)d_in[3];
    const float* bnb = (const float*)d_in[4];
    const float* W1 = (const float*)d_in[5];
    const float* W2 = (const float*)d_in[6];
    const float* W3 = (const float*)d_in[7];
    float* out = (float*)d_out;
    float* ws = (float*)d_ws;

    float* Wt    = ws;
    float* q     = ws + 128000;
    float* k     = ws + 238592;
    float* stats = ws + 349184;
    float* Qt    = ws + 349216;
    float* Kn    = ws + 459808;
    float* x4    = ws + 570400;
    float* t1    = ws + 943648;
    float* t2    = ws + 1047328;

    float* out0 = out;          // tanh(x5): 8000 floats
    float* att  = out + 8000;   // att: 216*1728 floats

    hipLaunchKernelGGL(k_wt,        dim3(16),   dim3(256), 0, stream, Wq, Wk, Wt);
    hipLaunchKernelGGL(k_qk,        dim3(216),  dim3(512), 0, stream, patches, Wt, q, k);
    hipLaunchKernelGGL(k_stats,     dim3(16),   dim3(256), 0, stream, q, k, stats);
    hipLaunchKernelGGL(k_norm,      dim3(864),  dim3(256), 0, stream, q, k, stats, bnw, bnb, Qt, Kn);
    hipLaunchKernelGGL(k_sparsemax, dim3(1728), dim3(256), 0, stream, Qt, Kn, att, x4);
    hipLaunchKernelGGL(k_tcl1,      dim3(405),  dim3(256), 0, stream, W1, x4, t1);
    hipLaunchKernelGGL(k_tcl2,      dim3(113),  dim3(256), 0, stream, W2, t1, t2);
    hipLaunchKernelGGL(k_tcl3,      dim3(32),   dim3(256), 0, stream, W3, t2, out0);
}